// Round 1
// 2552.034 us; speedup vs baseline: 1.4130x; 1.4130x over previous
//
#include <hip/hip_runtime.h>

// Chemprop BondMessagePassing, DEPTH=3, eval mode.
// R8 "P-trick": the x-part of the Wi GEMM is node-level, not edge-level.
//   P = x @ Wi_x^T + bi  (N x HD fp32 = 32e6 B, hosted in d_out; dead by k_out)
//   H0[e] = relu(P[src[e]] + ea[e] @ Wi_e^T)   -> 1 chunk (K=14 pad 16) + gather
// k_updb_p: 11 chunks (1 Q + 10 Wh) instead of 21. k_h0b_p: 1 chunk.
// ws layout identical to proven R6 MID (needs 194.6e6 <= 195e6 proven floor):
//   Hb bf16 @0 (160e6) | S fp32 @160e6 (32e6, reused S0/S1/M) | CSR @192e6.
// In-place Hb safety in k_updb_p unchanged from R6: rev pairs (e^1) are
// tile-local (TE=64 even), all rev reads consumed into LDS before the last
// barrier; stores only after it.

#define E_EDGES 500000
#define N_NODES 50000
#define HD      160
#define BD      14
#define K1      174
#define KO      320

#define TE 64
#define KC 16
#define NC2 (HD / KC)   // 10
#define WP  (HD + 8)    // Wt stride

// ---- bf16 helpers (RNE) ----
__device__ __forceinline__ unsigned short f2b(float v) {
    unsigned u = __float_as_uint(v);
    u += 0x7FFFu + ((u >> 16) & 1u);
    return (unsigned short)(u >> 16);
}
__device__ __forceinline__ float b2f(unsigned short h) {
    return __uint_as_float(((unsigned)h) << 16);
}

// ---------------------------------------------------------------------------
__global__ void k_zero(float* __restrict__ p, long n)
{
    const long i = (long)blockIdx.x * 1024 + (long)threadIdx.x * 4;
    if (i + 3 < n) *(float4*)(p + i) = make_float4(0.f, 0.f, 0.f, 0.f);
}

// ---------------------------------------------------------------------------
__device__ __forceinline__
void gemm_chunk(float acc[4][10], const float At[KC][TE + 4],
                const float Wt[KC][WP], int tr, int tc)
{
    #pragma unroll
    for (int k = 0; k < KC; ++k) {
        const float4 a  = *(const float4*)&At[k][tr * 4];
        const float* wp = &Wt[k][tc * 10];
        float w[10];
        #pragma unroll
        for (int j = 0; j < 10; j += 2) {
            const float2 w2 = *(const float2*)(wp + j);
            w[j] = w2.x; w[j + 1] = w2.y;
        }
        #pragma unroll
        for (int j = 0; j < 10; ++j) {
            acc[0][j] = fmaf(a.x, w[j], acc[0][j]);
            acc[1][j] = fmaf(a.y, w[j], acc[1][j]);
            acc[2][j] = fmaf(a.z, w[j], acc[2][j]);
            acc[3][j] = fmaf(a.w, w[j], acc[3][j]);
        }
    }
}

// ============================ CSR build ====================================
__global__ void k_csr_count(const int* __restrict__ dst, int* __restrict__ cnt)
{
    const int e = blockIdx.x * 256 + threadIdx.x;
    if (e < E_EDGES) atomicAdd(&cnt[dst[e]], 1);
}

#define BPT 49
__global__ __launch_bounds__(1024)
void k_csr_scan(const int* __restrict__ cnt, int* __restrict__ ptr)
{
    __shared__ int part[1024];
    const int t  = threadIdx.x;
    const int lo = t * BPT;
    const int hi = min(lo + BPT, N_NODES);
    int s = 0;
    for (int i = lo; i < hi; ++i) s += cnt[i];
    part[t] = s;
    __syncthreads();
    for (int off = 1; off < 1024; off <<= 1) {
        int v = 0;
        if (t >= off) v = part[t - off];
        __syncthreads();
        if (t >= off) part[t] += v;
        __syncthreads();
    }
    int run = (t == 0) ? 0 : part[t - 1];
    for (int i = lo; i < hi; ++i) { ptr[i] = run; run += cnt[i]; }
    if (t == 1023) ptr[N_NODES] = part[1023];
}

__global__ void k_csr_fill(const int* __restrict__ dst, const int* __restrict__ ptr,
                           int* __restrict__ cur, int* __restrict__ eid)
{
    const int e = blockIdx.x * 256 + threadIdx.x;
    if (e < E_EDGES) {
        const int d   = dst[e];
        const int pos = atomicAdd(&cur[d], 1);
        eid[ptr[d] + pos] = e;
    }
}

// ============================ node projection ==============================
// P[n] = Wi_x @ x[n] + bi   (fp32, NO relu; Wi_x = Wi[:, 0:HD], row stride K1)
__global__ __launch_bounds__(256, 2)
void k_nodeproj(const float* __restrict__ x, const float* __restrict__ Wi,
                const float* __restrict__ bi, float* __restrict__ P)
{
    __shared__ float At[KC][TE + 4];
    __shared__ float Wt[KC][WP];

    const int  t    = threadIdx.x;
    const long base = (long)blockIdx.x * TE;
    const int  se  = t >> 2;
    const int  skq = t & 3;
    const long gn  = base + se;
    const long gnc = (gn < N_NODES) ? gn : 0;
    const float* xrow = x + gnc * HD;
    const int tr = t >> 4, tc = t & 15;

    float acc[4][10];
    #pragma unroll
    for (int i = 0; i < 4; ++i)
        #pragma unroll
        for (int j = 0; j < 10; ++j) acc[i][j] = 0.f;

    for (int c = 0; c < NC2; ++c) {
        const int k0 = c * KC;
        __syncthreads();
        {
            const float4 v = *(const float4*)(xrow + k0 + skq * 4);
            At[skq * 4 + 0][se] = v.x;
            At[skq * 4 + 1][se] = v.y;
            At[skq * 4 + 2][se] = v.z;
            At[skq * 4 + 3][se] = v.w;
        }
        for (int i = t; i < HD * KC; i += 256) {
            const int kk = i & (KC - 1);
            const int h  = i >> 4;
            Wt[kk][h] = Wi[h * K1 + k0 + kk];
        }
        __syncthreads();
        gemm_chunk(acc, At, Wt, tr, tc);
    }
    #pragma unroll
    for (int i = 0; i < 4; ++i) {
        const long n = base + tr * 4 + i;
        if (n >= N_NODES) break;
        float* pp = P + n * HD + tc * 10;
        #pragma unroll
        for (int j = 0; j < 10; j += 2) {
            const float v0 = acc[i][j]     + bi[tc * 10 + j];
            const float v1 = acc[i][j + 1] + bi[tc * 10 + j + 1];
            *(float2*)(pp + j) = make_float2(v0, v1);
        }
    }
}

// ============================ H0 (P-trick) =================================
// Hb[e] = bf16(relu(P[src[e]] + Wi_e @ ea[e]))   — single K-chunk.
__global__ __launch_bounds__(256, 3)
void k_h0b_p(const float* __restrict__ ea, const int* __restrict__ src,
             const float* __restrict__ Wi, const float* __restrict__ P,
             unsigned short* __restrict__ Hb)
{
    __shared__ float At[KC][TE + 4];
    __shared__ float Wt[KC][WP];

    const int  t    = threadIdx.x;
    const long base = (long)blockIdx.x * TE;
    const int  se  = t >> 2;
    const int  skq = t & 3;
    const long ge  = base + se;
    const long gec = (ge < E_EDGES) ? ge : 0;
    const float* erow = ea + gec * BD;
    const int wk = t & 15, wh0 = t >> 4;
    const int tr = t >> 4, tc = t & 15;

    // epilogue src indices for this thread's 4 edges (broadcast-cached loads)
    int es[4];
    #pragma unroll
    for (int i = 0; i < 4; ++i) {
        const long e = base + tr * 4 + i;
        es[i] = (e < E_EDGES) ? src[e] : 0;
    }

    // stage ea chunk (K = 14 padded to 16)
    #pragma unroll
    for (int j = 0; j < 4; ++j) {
        const int k = skq * 4 + j;
        At[k][se] = (k < BD) ? erow[k] : 0.f;
    }
    // stage Wi_e (cols HD..HD+13)
    #pragma unroll
    for (int m = 0; m < 10; ++m)
        Wt[wk][wh0 + 16 * m] = (wk < BD) ? Wi[(wh0 + 16 * m) * K1 + HD + wk] : 0.f;

    // P gathers in flight while the chunk computes
    float pg[4][10];
    #pragma unroll
    for (int i = 0; i < 4; ++i) {
        const float* prow = P + (long)es[i] * HD + tc * 10;
        #pragma unroll
        for (int j = 0; j < 10; j += 2) {
            const float2 p2 = *(const float2*)(prow + j);
            pg[i][j] = p2.x; pg[i][j + 1] = p2.y;
        }
    }

    __syncthreads();
    float acc[4][10];
    #pragma unroll
    for (int i = 0; i < 4; ++i)
        #pragma unroll
        for (int j = 0; j < 10; ++j) acc[i][j] = 0.f;
    gemm_chunk(acc, At, Wt, tr, tc);

    #pragma unroll
    for (int i = 0; i < 4; ++i) {
        const long e = base + tr * 4 + i;
        if (e >= E_EDGES) break;
        unsigned short* hp = Hb + e * HD + tc * 10;
        #pragma unroll
        for (int j = 0; j < 10; j += 2) {
            float v0 = acc[i][j]     + pg[i][j];
            float v1 = acc[i][j + 1] + pg[i][j + 1];
            v0 = v0 > 0.f ? v0 : 0.f;
            v1 = v1 > 0.f ? v1 : 0.f;
            *(ushort2*)(hp + j) = make_ushort2(f2b(v0), f2b(v1));
        }
    }
}

// ============================ segment sum ==================================
template <bool FINAL>
__global__ void k_segb(const unsigned short* __restrict__ Hb,
                       const int* __restrict__ ptr, const int* __restrict__ eid,
                       const float* __restrict__ x, float* __restrict__ S)
{
    const int  lane = threadIdx.x & 63;
    const int  w    = threadIdx.x >> 6;
    const long n    = (long)blockIdx.x * 4 + w;
    if (n >= N_NODES) return;
    const int p0 = ptr[n], p1 = ptr[n + 1];
    float a0 = 0.f, a1 = 0.f, a2 = 0.f;
    for (int i = p0; i < p1; ++i) {
        const unsigned short* row = Hb + (long)eid[i] * HD;
        a0 += b2f(row[lane]);
        a1 += b2f(row[64 + lane]);
        if (lane < 32) a2 += b2f(row[128 + lane]);
    }
    const long sb = n * HD;
    if (FINAL) {
        float s = a0 + a1 + a2;
        #pragma unroll
        for (int off = 32; off > 0; off >>= 1) s += __shfl_xor(s, off, 64);
        if (s == 0.f) {
            S[sb + lane]      = x[sb + lane];
            S[sb + 64 + lane] = x[sb + 64 + lane];
            if (lane < 32) S[sb + 128 + lane] = x[sb + 128 + lane];
            return;
        }
    }
    S[sb + lane]      = a0;
    S[sb + 64 + lane] = a1;
    if (lane < 32) S[sb + 128 + lane] = a2;
}

// ============================ update (P-trick) =============================
// Hb[e] = bf16(relu( relu(P[src]+Wi_e@ea) + Wh @ (S[src]-Hb[e^1]) + bh ))
// 1 Q-chunk + 10 Wh chunks (was 11 + 10).
__global__ __launch_bounds__(256, 3)
void k_updb_p(const float* __restrict__ S, const float* __restrict__ ea,
              const int* __restrict__ src,
              const float* __restrict__ Wi, const float* __restrict__ Wh,
              const float* __restrict__ bh, const float* __restrict__ P,
              unsigned short* __restrict__ Hb)
{
    __shared__ float At[2][KC][TE + 4];
    __shared__ float Wt[2][KC][WP];

    const int  t    = threadIdx.x;
    const long base = (long)blockIdx.x * TE;
    const int  se   = t >> 2;
    const int  skq  = t & 3;
    const long ge   = base + se;
    const bool ev   = ge < E_EDGES;
    const long gec  = ev ? ge : 0;
    const int  sidx = ev ? src[gec] : 0;
    const float* erow = ea + gec * BD;
    const float* mrow = S  + (long)sidx * HD;
    const unsigned short* rrow = Hb + (gec ^ 1) * HD;
    const int wk = t & 15, wh0 = t >> 4;
    const int tr = t >> 4, tc = t & 15;

    // ---- early loads: epilogue src ids + long-latency pass-2 chunk-0 ----
    int es[4];
    #pragma unroll
    for (int i = 0; i < 4; ++i) {
        const long e = base + tr * 4 + i;
        es[i] = (e < E_EDGES) ? src[e] : 0;
    }
    float4  pa = *(const float4*)(mrow + skq * 4);
    ushort4 pr = *(const ushort4*)(rrow + skq * 4);

    float acc[4][10];
    #pragma unroll
    for (int i = 0; i < 4; ++i)
        #pragma unroll
        for (int j = 0; j < 10; ++j) acc[i][j] = 0.f;

    // ---- pass Q: one chunk over ea with Wi_e ----
    #pragma unroll
    for (int j = 0; j < 4; ++j) {
        const int k = skq * 4 + j;
        At[0][k][se] = (k < BD) ? erow[k] : 0.f;
    }
    #pragma unroll
    for (int m = 0; m < 10; ++m)
        Wt[0][wk][wh0 + 16 * m] = (wk < BD) ? Wi[(wh0 + 16 * m) * K1 + HD + wk] : 0.f;

    // P gathers in flight across the barrier + Q gemm
    float pg[4][10];
    #pragma unroll
    for (int i = 0; i < 4; ++i) {
        const float* prow = P + (long)es[i] * HD + tc * 10;
        #pragma unroll
        for (int j = 0; j < 10; j += 2) {
            const float2 p2 = *(const float2*)(prow + j);
            pg[i][j] = p2.x; pg[i][j + 1] = p2.y;
        }
    }

    __syncthreads();
    gemm_chunk(acc, At[0], Wt[0], tr, tc);

    // h0 = relu(Q + P) kept in pg
    #pragma unroll
    for (int i = 0; i < 4; ++i)
        #pragma unroll
        for (int j = 0; j < 10; ++j) {
            const float v = acc[i][j] + pg[i][j];
            pg[i][j] = v > 0.f ? v : 0.f;
            acc[i][j] = 0.f;
        }

    __syncthreads();   // all pass-Q LDS reads done before restaging buf 0

    // ---- pass 2: Wh over M = S[src] - Hb[e^1], double-buffered ----
    float pw[10];
    #pragma unroll
    for (int m = 0; m < 10; ++m) pw[m] = Wh[(wh0 + 16 * m) * HD + wk];

    for (int c = 0; c < NC2; ++c) {
        const int buf = c & 1;
        At[buf][skq * 4 + 0][se] = pa.x - b2f(pr.x);
        At[buf][skq * 4 + 1][se] = pa.y - b2f(pr.y);
        At[buf][skq * 4 + 2][se] = pa.z - b2f(pr.z);
        At[buf][skq * 4 + 3][se] = pa.w - b2f(pr.w);
        #pragma unroll
        for (int m = 0; m < 10; ++m) Wt[buf][wk][wh0 + 16 * m] = pw[m];
        __syncthreads();
        if (c + 1 < NC2) {
            const int kb = (c + 1) * KC + skq * 4;
            pa = *(const float4*)(mrow + kb);
            pr = *(const ushort4*)(rrow + kb);
            #pragma unroll
            for (int m = 0; m < 10; ++m)
                pw[m] = Wh[(wh0 + 16 * m) * HD + (c + 1) * KC + wk];
        }
        gemm_chunk(acc, At[buf], Wt[buf], tr, tc);
    }

    // epilogue: H = relu(h0 + WhM + bh)
    #pragma unroll
    for (int i = 0; i < 4; ++i) {
        const long e = base + tr * 4 + i;
        if (e >= E_EDGES) break;
        unsigned short* hp = Hb + e * HD + tc * 10;
        #pragma unroll
        for (int j = 0; j < 10; j += 2) {
            float v0 = pg[i][j]     + acc[i][j]     + bh[tc * 10 + j];
            float v1 = pg[i][j + 1] + acc[i][j + 1] + bh[tc * 10 + j + 1];
            v0 = v0 > 0.f ? v0 : 0.f;
            v1 = v1 > 0.f ? v1 : 0.f;
            *(ushort2*)(hp + j) = make_ushort2(f2b(v0), f2b(v1));
        }
    }
}

// ============================ output =======================================
__global__ __launch_bounds__(256, 2)
void k_out(const float* __restrict__ x, const float* __restrict__ Mg,
           const float* __restrict__ Wo, const float* __restrict__ bo,
           float* __restrict__ out)
{
    __shared__ float At[KC][TE + 4];
    __shared__ float Wt[KC][WP];

    const int  t    = threadIdx.x;
    const long base = (long)blockIdx.x * TE;
    const int  se  = t >> 2;
    const int  skq = t & 3;
    const long gn  = base + se;
    const bool ev  = gn < N_NODES;
    const long gnc = ev ? gn : 0;
    const float* xrow = x  + gnc * HD;
    const float* mrow = Mg + gnc * HD;
    const int tr = t >> 4, tc = t & 15;

    float acc[4][10];
    #pragma unroll
    for (int i = 0; i < 4; ++i)
        #pragma unroll
        for (int j = 0; j < 10; ++j) acc[i][j] = 0.f;

    for (int c = 0; c < KO / KC; ++c) {
        const int k0 = c * KC;
        __syncthreads();
        {
            const int kb = k0 + skq * 4;
            const float4 v = (kb < HD) ? *(const float4*)(xrow + kb)
                                       : *(const float4*)(mrow + (kb - HD));
            At[skq * 4 + 0][se] = v.x;
            At[skq * 4 + 1][se] = v.y;
            At[skq * 4 + 2][se] = v.z;
            At[skq * 4 + 3][se] = v.w;
        }
        for (int i = t; i < HD * KC; i += 256) {
            const int kk = i & (KC - 1);
            const int h  = i >> 4;
            Wt[kk][h] = Wo[h * KO + k0 + kk];
        }
        __syncthreads();
        gemm_chunk(acc, At, Wt, tr, tc);
    }
    #pragma unroll
    for (int i = 0; i < 4; ++i) {
        const long n = base + tr * 4 + i;
        if (n >= N_NODES) break;
        float* op = out + n * HD + tc * 10;
        #pragma unroll
        for (int j = 0; j < 10; j += 2) {
            float v0 = acc[i][j]     + bo[tc * 10 + j];
            float v1 = acc[i][j + 1] + bo[tc * 10 + j + 1];
            v0 = v0 > 0.f ? v0 : 0.f;
            v1 = v1 > 0.f ? v1 : 0.f;
            *(float2*)(op + j) = make_float2(v0, v1);
        }
    }
}

// ---------------------------------------------------------------------------
extern "C" void kernel_launch(void* const* d_in, const int* in_sizes, int n_in,
                              void* d_out, int out_size, void* d_ws, size_t ws_size,
                              hipStream_t stream)
{
    const float* x  = (const float*)d_in[0];
    const float* ea = (const float*)d_in[1];
    const int*   ei = (const int*)d_in[2];
    const float* Wi = (const float*)d_in[4];
    const float* bi = (const float*)d_in[5];
    const float* Wh = (const float*)d_in[6];
    const float* bh = (const float*)d_in[7];
    const float* Wo = (const float*)d_in[8];
    const float* bo = (const float*)d_in[9];
    float* out = (float*)d_out;

    const int* src = ei;
    const int* dst = ei + E_EDGES;

    const int gE  = (E_EDGES + TE - 1) / TE;      // 7813
    const int gN  = (N_NODES + TE - 1) / TE;      // 782
    const int gF  = (N_NODES + 3) / 4;            // 12500
    const int gEe = (E_EDGES + 255) / 256;        // 1954

    // ws layout = proven R6 MID (194.6e6 needed; ws >= 195e6 proven).
    char* w = (char*)d_ws;
    unsigned short* Hb = (unsigned short*)(w);
    float* Sx  = (float*)(w + 160000000);
    int*   ptr = (int*)  (w + 192000000);
    int*   cnt = (int*)  (w + 192200016);
    int*   cur = (int*)  (w + 192400016);
    int*   eid = (int*)  (w + 192600016);
    // P (N x HD fp32 = 32e6 B) lives in d_out; dead before k_out writes out.
    float* Pn  = (float*)d_out;

    k_zero<<<(100000 + 1023) / 1024, 256, 0, stream>>>((float*)cnt, 100000);
    k_csr_count<<<gEe, 256, 0, stream>>>(dst, cnt);
    k_csr_scan<<<1, 1024, 0, stream>>>(cnt, ptr);
    k_csr_fill<<<gEe, 256, 0, stream>>>(dst, ptr, cur, eid);

    k_nodeproj<<<gN, 256, 0, stream>>>(x, Wi, bi, Pn);
    k_h0b_p<<<gE, 256, 0, stream>>>(ea, src, Wi, Pn, Hb);              // H0
    k_segb<false><<<gF, 256, 0, stream>>>(Hb, ptr, eid, x, Sx);        // S0
    k_updb_p<<<gE, 256, 0, stream>>>(Sx, ea, src, Wi, Wh, bh, Pn, Hb); // H1
    k_segb<false><<<gF, 256, 0, stream>>>(Hb, ptr, eid, x, Sx);        // S1
    k_updb_p<<<gE, 256, 0, stream>>>(Sx, ea, src, Wi, Wh, bh, Pn, Hb); // H2
    k_segb<true ><<<gF, 256, 0, stream>>>(Hb, ptr, eid, x, Sx);        // M
    k_out<<<gN, 256, 0, stream>>>(x, Sx, Wo, bo, out);
}

// Round 2
// 1936.609 us; speedup vs baseline: 1.8620x; 1.3178x over previous
//
#include <hip/hip_runtime.h>

// Chemprop BondMessagePassing, DEPTH=3, eval mode.
// R9: gather-diet round.
//  - UPD iter 1 reads h0 directly from Hb (it still holds H0): no P gather,
//    no Q chunk. Same-thread same-address read-before-write -> race-free.
//  - P and middle segsums S0/S1 stored bf16 (Pb, Sb in d_out: 16e6+16e6=32e6
//    exactly). Halves the 640B random gathers to 320B.
//  - Final segsum stays fp32 + x-fallback into ws (Mf); k_out unchanged.
// ws layout (proven >=195e6): Hb bf16 @0 (160e6) | Mf fp32 @160e6 (32e6) |
//   CSR @192e6 (~2.6e6).

#define E_EDGES 500000
#define N_NODES 50000
#define HD      160
#define BD      14
#define K1      174
#define KO      320

#define TE 64
#define KC 16
#define NC2 (HD / KC)   // 10
#define WP  (HD + 8)    // Wt stride

// ---- bf16 helpers (RNE) ----
__device__ __forceinline__ unsigned short f2b(float v) {
    unsigned u = __float_as_uint(v);
    u += 0x7FFFu + ((u >> 16) & 1u);
    return (unsigned short)(u >> 16);
}
__device__ __forceinline__ float b2f(unsigned short h) {
    return __uint_as_float(((unsigned)h) << 16);
}

// ---------------------------------------------------------------------------
__global__ void k_zero(float* __restrict__ p, long n)
{
    const long i = (long)blockIdx.x * 1024 + (long)threadIdx.x * 4;
    if (i + 3 < n) *(float4*)(p + i) = make_float4(0.f, 0.f, 0.f, 0.f);
}

// ---------------------------------------------------------------------------
__device__ __forceinline__
void gemm_chunk(float acc[4][10], const float At[KC][TE + 4],
                const float Wt[KC][WP], int tr, int tc)
{
    #pragma unroll
    for (int k = 0; k < KC; ++k) {
        const float4 a  = *(const float4*)&At[k][tr * 4];
        const float* wp = &Wt[k][tc * 10];
        float w[10];
        #pragma unroll
        for (int j = 0; j < 10; j += 2) {
            const float2 w2 = *(const float2*)(wp + j);
            w[j] = w2.x; w[j + 1] = w2.y;
        }
        #pragma unroll
        for (int j = 0; j < 10; ++j) {
            acc[0][j] = fmaf(a.x, w[j], acc[0][j]);
            acc[1][j] = fmaf(a.y, w[j], acc[1][j]);
            acc[2][j] = fmaf(a.z, w[j], acc[2][j]);
            acc[3][j] = fmaf(a.w, w[j], acc[3][j]);
        }
    }
}

// ============================ CSR build ====================================
__global__ void k_csr_count(const int* __restrict__ dst, int* __restrict__ cnt)
{
    const int e = blockIdx.x * 256 + threadIdx.x;
    if (e < E_EDGES) atomicAdd(&cnt[dst[e]], 1);
}

#define BPT 49
__global__ __launch_bounds__(1024)
void k_csr_scan(const int* __restrict__ cnt, int* __restrict__ ptr)
{
    __shared__ int part[1024];
    const int t  = threadIdx.x;
    const int lo = t * BPT;
    const int hi = min(lo + BPT, N_NODES);
    int s = 0;
    for (int i = lo; i < hi; ++i) s += cnt[i];
    part[t] = s;
    __syncthreads();
    for (int off = 1; off < 1024; off <<= 1) {
        int v = 0;
        if (t >= off) v = part[t - off];
        __syncthreads();
        if (t >= off) part[t] += v;
        __syncthreads();
    }
    int run = (t == 0) ? 0 : part[t - 1];
    for (int i = lo; i < hi; ++i) { ptr[i] = run; run += cnt[i]; }
    if (t == 1023) ptr[N_NODES] = part[1023];
}

__global__ void k_csr_fill(const int* __restrict__ dst, const int* __restrict__ ptr,
                           int* __restrict__ cur, int* __restrict__ eid)
{
    const int e = blockIdx.x * 256 + threadIdx.x;
    if (e < E_EDGES) {
        const int d   = dst[e];
        const int pos = atomicAdd(&cur[d], 1);
        eid[ptr[d] + pos] = e;
    }
}

// ============================ node projection ==============================
// Pb[n] = bf16(Wi_x @ x[n] + bi)   (NO relu; Wi_x = Wi[:, 0:HD], stride K1)
__global__ __launch_bounds__(256, 2)
void k_nodeproj(const float* __restrict__ x, const float* __restrict__ Wi,
                const float* __restrict__ bi, unsigned short* __restrict__ Pb)
{
    __shared__ float At[KC][TE + 4];
    __shared__ float Wt[KC][WP];

    const int  t    = threadIdx.x;
    const long base = (long)blockIdx.x * TE;
    const int  se  = t >> 2;
    const int  skq = t & 3;
    const long gn  = base + se;
    const long gnc = (gn < N_NODES) ? gn : 0;
    const float* xrow = x + gnc * HD;
    const int tr = t >> 4, tc = t & 15;

    float acc[4][10];
    #pragma unroll
    for (int i = 0; i < 4; ++i)
        #pragma unroll
        for (int j = 0; j < 10; ++j) acc[i][j] = 0.f;

    for (int c = 0; c < NC2; ++c) {
        const int k0 = c * KC;
        __syncthreads();
        {
            const float4 v = *(const float4*)(xrow + k0 + skq * 4);
            At[skq * 4 + 0][se] = v.x;
            At[skq * 4 + 1][se] = v.y;
            At[skq * 4 + 2][se] = v.z;
            At[skq * 4 + 3][se] = v.w;
        }
        for (int i = t; i < HD * KC; i += 256) {
            const int kk = i & (KC - 1);
            const int h  = i >> 4;
            Wt[kk][h] = Wi[h * K1 + k0 + kk];
        }
        __syncthreads();
        gemm_chunk(acc, At, Wt, tr, tc);
    }
    #pragma unroll
    for (int i = 0; i < 4; ++i) {
        const long n = base + tr * 4 + i;
        if (n >= N_NODES) break;
        unsigned short* pp = Pb + n * HD + tc * 10;
        #pragma unroll
        for (int j = 0; j < 10; j += 2) {
            const float v0 = acc[i][j]     + bi[tc * 10 + j];
            const float v1 = acc[i][j + 1] + bi[tc * 10 + j + 1];
            *(ushort2*)(pp + j) = make_ushort2(f2b(v0), f2b(v1));
        }
    }
}

// ============================ H0 ===========================================
// Hb[e] = bf16(relu(Pb[src[e]] + Wi_e @ ea[e]))   — single K-chunk.
__global__ __launch_bounds__(256, 3)
void k_h0b_p(const float* __restrict__ ea, const int* __restrict__ src,
             const float* __restrict__ Wi, const unsigned short* __restrict__ Pb,
             unsigned short* __restrict__ Hb)
{
    __shared__ float At[KC][TE + 4];
    __shared__ float Wt[KC][WP];

    const int  t    = threadIdx.x;
    const long base = (long)blockIdx.x * TE;
    const int  se  = t >> 2;
    const int  skq = t & 3;
    const long ge  = base + se;
    const long gec = (ge < E_EDGES) ? ge : 0;
    const float* erow = ea + gec * BD;
    const int wk = t & 15, wh0 = t >> 4;
    const int tr = t >> 4, tc = t & 15;

    int es[4];
    #pragma unroll
    for (int i = 0; i < 4; ++i) {
        const long e = base + tr * 4 + i;
        es[i] = (e < E_EDGES) ? src[e] : 0;
    }

    #pragma unroll
    for (int j = 0; j < 4; ++j) {
        const int k = skq * 4 + j;
        At[k][se] = (k < BD) ? erow[k] : 0.f;
    }
    #pragma unroll
    for (int m = 0; m < 10; ++m)
        Wt[wk][wh0 + 16 * m] = (wk < BD) ? Wi[(wh0 + 16 * m) * K1 + HD + wk] : 0.f;

    // Pb gathers in flight across the barrier + gemm
    ushort2 praw[4][5];
    #pragma unroll
    for (int i = 0; i < 4; ++i) {
        const unsigned short* prow = Pb + (long)es[i] * HD + tc * 10;
        #pragma unroll
        for (int q = 0; q < 5; ++q) praw[i][q] = *(const ushort2*)(prow + 2 * q);
    }

    __syncthreads();
    float acc[4][10];
    #pragma unroll
    for (int i = 0; i < 4; ++i)
        #pragma unroll
        for (int j = 0; j < 10; ++j) acc[i][j] = 0.f;
    gemm_chunk(acc, At, Wt, tr, tc);

    #pragma unroll
    for (int i = 0; i < 4; ++i) {
        const long e = base + tr * 4 + i;
        if (e >= E_EDGES) break;
        unsigned short* hp = Hb + e * HD + tc * 10;
        #pragma unroll
        for (int j = 0; j < 10; j += 2) {
            float v0 = acc[i][j]     + b2f(praw[i][j / 2].x);
            float v1 = acc[i][j + 1] + b2f(praw[i][j / 2].y);
            v0 = v0 > 0.f ? v0 : 0.f;
            v1 = v1 > 0.f ? v1 : 0.f;
            *(ushort2*)(hp + j) = make_ushort2(f2b(v0), f2b(v1));
        }
    }
}

// ============================ segment sum ==================================
// FINAL=0: write bf16 Sb. FINAL=1: write fp32 S with sum==0 -> x fallback.
template <int FINAL>
__global__ void k_segb(const unsigned short* __restrict__ Hb,
                       const int* __restrict__ ptr, const int* __restrict__ eid,
                       const float* __restrict__ x,
                       unsigned short* __restrict__ Sb, float* __restrict__ S)
{
    const int  lane = threadIdx.x & 63;
    const int  w    = threadIdx.x >> 6;
    const long n    = (long)blockIdx.x * 4 + w;
    if (n >= N_NODES) return;
    const int p0 = ptr[n], p1 = ptr[n + 1];
    float a0 = 0.f, a1 = 0.f, a2 = 0.f;
    for (int i = p0; i < p1; ++i) {
        const unsigned short* row = Hb + (long)eid[i] * HD;
        a0 += b2f(row[lane]);
        a1 += b2f(row[64 + lane]);
        if (lane < 32) a2 += b2f(row[128 + lane]);
    }
    const long sb = n * HD;
    if (FINAL) {
        float s = a0 + a1 + a2;
        #pragma unroll
        for (int off = 32; off > 0; off >>= 1) s += __shfl_xor(s, off, 64);
        if (s == 0.f) {
            S[sb + lane]      = x[sb + lane];
            S[sb + 64 + lane] = x[sb + 64 + lane];
            if (lane < 32) S[sb + 128 + lane] = x[sb + 128 + lane];
            return;
        }
        S[sb + lane]      = a0;
        S[sb + 64 + lane] = a1;
        if (lane < 32) S[sb + 128 + lane] = a2;
    } else {
        Sb[sb + lane]      = f2b(a0);
        Sb[sb + 64 + lane] = f2b(a1);
        if (lane < 32) Sb[sb + 128 + lane] = f2b(a2);
    }
}

// ============================ update =======================================
// FIRST=1: h0 read straight from Hb (it holds H0). No P gather, no Q chunk.
// FIRST=0: h0 = relu(Pb[src] + Wi_e @ ea)  (1 Q chunk + bf16 P gather).
// Then: Hb[e] = bf16(relu(h0 + Wh @ (Sb[src] - Hb[e^1]) + bh)).
// In-place Hb safe: rev pairs tile-local; h0 reads are the same thread's own
// store addresses; all global Hb reads consumed before the last barrier,
// stores only after it.
template <int FIRST>
__global__ __launch_bounds__(256, 3)
void k_updb_pb(const unsigned short* __restrict__ Sb,
               const float* __restrict__ ea, const int* __restrict__ src,
               const float* __restrict__ Wi, const float* __restrict__ Wh,
               const float* __restrict__ bh,
               const unsigned short* __restrict__ Pb,
               unsigned short* __restrict__ Hb)
{
    __shared__ float At[2][KC][TE + 4];
    __shared__ float Wt[2][KC][WP];

    const int  t    = threadIdx.x;
    const long base = (long)blockIdx.x * TE;
    const int  se   = t >> 2;
    const int  skq  = t & 3;
    const long ge   = base + se;
    const bool ev   = ge < E_EDGES;
    const long gec  = ev ? ge : 0;
    const int  sidx = ev ? src[gec] : 0;
    const unsigned short* mrow = Sb + (long)sidx * HD;
    const unsigned short* rrow = Hb + (gec ^ 1) * HD;
    const int wk = t & 15, wh0 = t >> 4;
    const int tr = t >> 4, tc = t & 15;

    // ---- early loads ----
    ushort2 hraw[4][5];          // FIRST: h0 rows (own Hb rows)
    int es[4];
    if (FIRST) {
        #pragma unroll
        for (int i = 0; i < 4; ++i) {
            const long e = base + tr * 4 + i;
            const unsigned short* hp = Hb + ((e < E_EDGES) ? e : 0) * HD + tc * 10;
            #pragma unroll
            for (int q = 0; q < 5; ++q) hraw[i][q] = *(const ushort2*)(hp + 2 * q);
        }
    } else {
        #pragma unroll
        for (int i = 0; i < 4; ++i) {
            const long e = base + tr * 4 + i;
            es[i] = (e < E_EDGES) ? src[e] : 0;
        }
    }
    ushort4 pm = *(const ushort4*)(mrow + skq * 4);
    ushort4 pr = *(const ushort4*)(rrow + skq * 4);

    float acc[4][10];
    #pragma unroll
    for (int i = 0; i < 4; ++i)
        #pragma unroll
        for (int j = 0; j < 10; ++j) acc[i][j] = 0.f;

    float pg[4][10];             // !FIRST: h0 = relu(Pb + q)
    if (!FIRST) {
        const float* erow = ea + gec * BD;
        #pragma unroll
        for (int j = 0; j < 4; ++j) {
            const int k = skq * 4 + j;
            At[0][k][se] = (k < BD) ? erow[k] : 0.f;
        }
        #pragma unroll
        for (int m = 0; m < 10; ++m)
            Wt[0][wk][wh0 + 16 * m] = (wk < BD) ? Wi[(wh0 + 16 * m) * K1 + HD + wk] : 0.f;

        ushort2 praw[4][5];
        #pragma unroll
        for (int i = 0; i < 4; ++i) {
            const unsigned short* prow = Pb + (long)es[i] * HD + tc * 10;
            #pragma unroll
            for (int q = 0; q < 5; ++q) praw[i][q] = *(const ushort2*)(prow + 2 * q);
        }

        __syncthreads();
        gemm_chunk(acc, At[0], Wt[0], tr, tc);

        #pragma unroll
        for (int i = 0; i < 4; ++i)
            #pragma unroll
            for (int j = 0; j < 10; ++j) {
                const float pv = b2f((j & 1) ? praw[i][j / 2].y : praw[i][j / 2].x);
                const float v  = acc[i][j] + pv;
                pg[i][j] = v > 0.f ? v : 0.f;
                acc[i][j] = 0.f;
            }
        __syncthreads();   // all Q-chunk LDS reads done before restaging buf 0
    }

    // ---- Wh pass: M = Sb[src] - Hb[e^1], double-buffered ----
    float pw[10];
    #pragma unroll
    for (int m = 0; m < 10; ++m) pw[m] = Wh[(wh0 + 16 * m) * HD + wk];

    for (int c = 0; c < NC2; ++c) {
        const int buf = c & 1;
        At[buf][skq * 4 + 0][se] = b2f(pm.x) - b2f(pr.x);
        At[buf][skq * 4 + 1][se] = b2f(pm.y) - b2f(pr.y);
        At[buf][skq * 4 + 2][se] = b2f(pm.z) - b2f(pr.z);
        At[buf][skq * 4 + 3][se] = b2f(pm.w) - b2f(pr.w);
        #pragma unroll
        for (int m = 0; m < 10; ++m) Wt[buf][wk][wh0 + 16 * m] = pw[m];
        __syncthreads();
        if (c + 1 < NC2) {
            const int kb = (c + 1) * KC + skq * 4;
            pm = *(const ushort4*)(mrow + kb);
            pr = *(const ushort4*)(rrow + kb);
            #pragma unroll
            for (int m = 0; m < 10; ++m)
                pw[m] = Wh[(wh0 + 16 * m) * HD + (c + 1) * KC + wk];
        }
        gemm_chunk(acc, At[buf], Wt[buf], tr, tc);
    }

    // ---- epilogue: H = relu(h0 + WhM + bh) ----
    #pragma unroll
    for (int i = 0; i < 4; ++i) {
        const long e = base + tr * 4 + i;
        if (e >= E_EDGES) break;
        unsigned short* hp = Hb + e * HD + tc * 10;
        #pragma unroll
        for (int j = 0; j < 10; j += 2) {
            const float h0a = FIRST ? b2f(hraw[i][j / 2].x) : pg[i][j];
            const float h0b = FIRST ? b2f(hraw[i][j / 2].y) : pg[i][j + 1];
            float v0 = h0a + acc[i][j]     + bh[tc * 10 + j];
            float v1 = h0b + acc[i][j + 1] + bh[tc * 10 + j + 1];
            v0 = v0 > 0.f ? v0 : 0.f;
            v1 = v1 > 0.f ? v1 : 0.f;
            *(ushort2*)(hp + j) = make_ushort2(f2b(v0), f2b(v1));
        }
    }
}

// ============================ output =======================================
__global__ __launch_bounds__(256, 2)
void k_out(const float* __restrict__ x, const float* __restrict__ Mg,
           const float* __restrict__ Wo, const float* __restrict__ bo,
           float* __restrict__ out)
{
    __shared__ float At[KC][TE + 4];
    __shared__ float Wt[KC][WP];

    const int  t    = threadIdx.x;
    const long base = (long)blockIdx.x * TE;
    const int  se  = t >> 2;
    const int  skq = t & 3;
    const long gn  = base + se;
    const bool ev  = gn < N_NODES;
    const long gnc = ev ? gn : 0;
    const float* xrow = x  + gnc * HD;
    const float* mrow = Mg + gnc * HD;
    const int tr = t >> 4, tc = t & 15;

    float acc[4][10];
    #pragma unroll
    for (int i = 0; i < 4; ++i)
        #pragma unroll
        for (int j = 0; j < 10; ++j) acc[i][j] = 0.f;

    for (int c = 0; c < KO / KC; ++c) {
        const int k0 = c * KC;
        __syncthreads();
        {
            const int kb = k0 + skq * 4;
            const float4 v = (kb < HD) ? *(const float4*)(xrow + kb)
                                       : *(const float4*)(mrow + (kb - HD));
            At[skq * 4 + 0][se] = v.x;
            At[skq * 4 + 1][se] = v.y;
            At[skq * 4 + 2][se] = v.z;
            At[skq * 4 + 3][se] = v.w;
        }
        for (int i = t; i < HD * KC; i += 256) {
            const int kk = i & (KC - 1);
            const int h  = i >> 4;
            Wt[kk][h] = Wo[h * KO + k0 + kk];
        }
        __syncthreads();
        gemm_chunk(acc, At, Wt, tr, tc);
    }
    #pragma unroll
    for (int i = 0; i < 4; ++i) {
        const long n = base + tr * 4 + i;
        if (n >= N_NODES) break;
        float* op = out + n * HD + tc * 10;
        #pragma unroll
        for (int j = 0; j < 10; j += 2) {
            float v0 = acc[i][j]     + bo[tc * 10 + j];
            float v1 = acc[i][j + 1] + bo[tc * 10 + j + 1];
            v0 = v0 > 0.f ? v0 : 0.f;
            v1 = v1 > 0.f ? v1 : 0.f;
            *(float2*)(op + j) = make_float2(v0, v1);
        }
    }
}

// ---------------------------------------------------------------------------
extern "C" void kernel_launch(void* const* d_in, const int* in_sizes, int n_in,
                              void* d_out, int out_size, void* d_ws, size_t ws_size,
                              hipStream_t stream)
{
    const float* x  = (const float*)d_in[0];
    const float* ea = (const float*)d_in[1];
    const int*   ei = (const int*)d_in[2];
    const float* Wi = (const float*)d_in[4];
    const float* bi = (const float*)d_in[5];
    const float* Wh = (const float*)d_in[6];
    const float* bh = (const float*)d_in[7];
    const float* Wo = (const float*)d_in[8];
    const float* bo = (const float*)d_in[9];
    float* out = (float*)d_out;

    const int* src = ei;
    const int* dst = ei + E_EDGES;

    const int gE  = (E_EDGES + TE - 1) / TE;      // 7813
    const int gN  = (N_NODES + TE - 1) / TE;      // 782
    const int gF  = (N_NODES + 3) / 4;            // 12500
    const int gEe = (E_EDGES + 255) / 256;        // 1954

    // ws: Hb bf16 (160e6) | Mf fp32 (32e6) | CSR (~2.6e6)  -> 194.6e6 proven
    char* w = (char*)d_ws;
    unsigned short* Hb = (unsigned short*)(w);
    float* Mf  = (float*)(w + 160000000);
    int*   ptr = (int*)  (w + 192000000);
    int*   cnt = (int*)  (w + 192200016);
    int*   cur = (int*)  (w + 192400016);
    int*   eid = (int*)  (w + 192600016);
    // d_out hosts Pb (16e6) + Sb (16e6) until k_out.
    unsigned short* Pb = (unsigned short*)d_out;
    unsigned short* Sb = (unsigned short*)((char*)d_out + 16000000);

    k_zero<<<(100000 + 1023) / 1024, 256, 0, stream>>>((float*)cnt, 100000);
    k_csr_count<<<gEe, 256, 0, stream>>>(dst, cnt);
    k_csr_scan<<<1, 1024, 0, stream>>>(cnt, ptr);
    k_csr_fill<<<gEe, 256, 0, stream>>>(dst, ptr, cur, eid);

    k_nodeproj<<<gN, 256, 0, stream>>>(x, Wi, bi, Pb);
    k_h0b_p<<<gE, 256, 0, stream>>>(ea, src, Wi, Pb, Hb);                    // H0
    k_segb<0><<<gF, 256, 0, stream>>>(Hb, ptr, eid, x, Sb, nullptr);         // S0
    k_updb_pb<1><<<gE, 256, 0, stream>>>(Sb, ea, src, Wi, Wh, bh, Pb, Hb);   // H1
    k_segb<0><<<gF, 256, 0, stream>>>(Hb, ptr, eid, x, Sb, nullptr);         // S1
    k_updb_pb<0><<<gE, 256, 0, stream>>>(Sb, ea, src, Wi, Wh, bh, Pb, Hb);   // H2
    k_segb<1><<<gF, 256, 0, stream>>>(Hb, ptr, eid, x, nullptr, Mf);         // M
    k_out<<<gN, 256, 0, stream>>>(x, Mf, Wo, bo, out);
}

// Round 3
// 1072.603 us; speedup vs baseline: 3.3619x; 1.8055x over previous
//
#include <hip/hip_runtime.h>

// Chemprop BondMessagePassing, DEPTH=3, eval mode.
// R10: MFMA update kernels.
//  - k_updm1/k_updm2 replace the vector k_updb_pb: Wh GEMM via
//    v_mfma_f32_16x16x16_bf16 (A row=lane%16, k=(lane/16)*4+j; C/D col=lane&15,
//    row=(lane>>4)*4+reg). A-operand (M = Sb[src] - Hb[e^1]) is built in
//    registers straight from global bf16 loads -> NO LDS staging, NO barriers
//    in the K loop. Only Wh lives in LDS (bf16, stride 164 shorts -> 16-lane
//    conflict-free: 82 dwords * c mod 32 all-distinct).
//  - Each wave owns 16 edges (closed under e^1) -> in-place Hb race-free.
//  - iter1 (updm1): h0 read from Hb itself (still holds H0) at epilogue.
//  - iter2 (updm2): h0 = relu(Pb[src] + one MFMA step of ea @ Wi_e^T).
// ws layout (proven >=195e6): Hb bf16 @0 (160e6) | Mf fp32 @160e6 (32e6) |
//   CSR @192e6. d_out hosts Pb(16e6)+Sb(16e6) until k_out.

#define E_EDGES 500000
#define N_NODES 50000
#define HD      160
#define BD      14
#define K1      174
#define KO      320

#define TE 64
#define KC 16
#define NC2 (HD / KC)   // 10
#define WP  (HD + 8)    // Wt stride (vector kernels)

#define TM   128        // edges per MFMA block (8 waves x 16)
#define WHP  164        // Whl padded k-stride (shorts)
#define WIEP 20         // Wie padded k-stride (shorts)

typedef __attribute__((ext_vector_type(4))) short v4s;
typedef __attribute__((ext_vector_type(4))) float v4f;

// ---- bf16 helpers (RNE) ----
__device__ __forceinline__ unsigned short f2b(float v) {
    unsigned u = __float_as_uint(v);
    u += 0x7FFFu + ((u >> 16) & 1u);
    return (unsigned short)(u >> 16);
}
__device__ __forceinline__ float b2f(unsigned short h) {
    return __uint_as_float(((unsigned)h) << 16);
}

__device__ __forceinline__ v4s mdiff(ushort4 s, ushort4 r) {
    v4s a;
    a[0] = (short)f2b(b2f(s.x) - b2f(r.x));
    a[1] = (short)f2b(b2f(s.y) - b2f(r.y));
    a[2] = (short)f2b(b2f(s.z) - b2f(r.z));
    a[3] = (short)f2b(b2f(s.w) - b2f(r.w));
    return a;
}

// ---------------------------------------------------------------------------
__global__ void k_zero(float* __restrict__ p, long n)
{
    const long i = (long)blockIdx.x * 1024 + (long)threadIdx.x * 4;
    if (i + 3 < n) *(float4*)(p + i) = make_float4(0.f, 0.f, 0.f, 0.f);
}

// ---------------------------------------------------------------------------
__device__ __forceinline__
void gemm_chunk(float acc[4][10], const float At[KC][TE + 4],
                const float Wt[KC][WP], int tr, int tc)
{
    #pragma unroll
    for (int k = 0; k < KC; ++k) {
        const float4 a  = *(const float4*)&At[k][tr * 4];
        const float* wp = &Wt[k][tc * 10];
        float w[10];
        #pragma unroll
        for (int j = 0; j < 10; j += 2) {
            const float2 w2 = *(const float2*)(wp + j);
            w[j] = w2.x; w[j + 1] = w2.y;
        }
        #pragma unroll
        for (int j = 0; j < 10; ++j) {
            acc[0][j] = fmaf(a.x, w[j], acc[0][j]);
            acc[1][j] = fmaf(a.y, w[j], acc[1][j]);
            acc[2][j] = fmaf(a.z, w[j], acc[2][j]);
            acc[3][j] = fmaf(a.w, w[j], acc[3][j]);
        }
    }
}

// ============================ CSR build ====================================
__global__ void k_csr_count(const int* __restrict__ dst, int* __restrict__ cnt)
{
    const int e = blockIdx.x * 256 + threadIdx.x;
    if (e < E_EDGES) atomicAdd(&cnt[dst[e]], 1);
}

#define BPT 49
__global__ __launch_bounds__(1024)
void k_csr_scan(const int* __restrict__ cnt, int* __restrict__ ptr)
{
    __shared__ int part[1024];
    const int t  = threadIdx.x;
    const int lo = t * BPT;
    const int hi = min(lo + BPT, N_NODES);
    int s = 0;
    for (int i = lo; i < hi; ++i) s += cnt[i];
    part[t] = s;
    __syncthreads();
    for (int off = 1; off < 1024; off <<= 1) {
        int v = 0;
        if (t >= off) v = part[t - off];
        __syncthreads();
        if (t >= off) part[t] += v;
        __syncthreads();
    }
    int run = (t == 0) ? 0 : part[t - 1];
    for (int i = lo; i < hi; ++i) { ptr[i] = run; run += cnt[i]; }
    if (t == 1023) ptr[N_NODES] = part[1023];
}

__global__ void k_csr_fill(const int* __restrict__ dst, const int* __restrict__ ptr,
                           int* __restrict__ cur, int* __restrict__ eid)
{
    const int e = blockIdx.x * 256 + threadIdx.x;
    if (e < E_EDGES) {
        const int d   = dst[e];
        const int pos = atomicAdd(&cur[d], 1);
        eid[ptr[d] + pos] = e;
    }
}

// ============================ node projection ==============================
// Pb[n] = bf16(Wi_x @ x[n] + bi)   (NO relu; Wi_x = Wi[:, 0:HD], stride K1)
__global__ __launch_bounds__(256, 2)
void k_nodeproj(const float* __restrict__ x, const float* __restrict__ Wi,
                const float* __restrict__ bi, unsigned short* __restrict__ Pb)
{
    __shared__ float At[KC][TE + 4];
    __shared__ float Wt[KC][WP];

    const int  t    = threadIdx.x;
    const long base = (long)blockIdx.x * TE;
    const int  se  = t >> 2;
    const int  skq = t & 3;
    const long gn  = base + se;
    const long gnc = (gn < N_NODES) ? gn : 0;
    const float* xrow = x + gnc * HD;
    const int tr = t >> 4, tc = t & 15;

    float acc[4][10];
    #pragma unroll
    for (int i = 0; i < 4; ++i)
        #pragma unroll
        for (int j = 0; j < 10; ++j) acc[i][j] = 0.f;

    for (int c = 0; c < NC2; ++c) {
        const int k0 = c * KC;
        __syncthreads();
        {
            const float4 v = *(const float4*)(xrow + k0 + skq * 4);
            At[skq * 4 + 0][se] = v.x;
            At[skq * 4 + 1][se] = v.y;
            At[skq * 4 + 2][se] = v.z;
            At[skq * 4 + 3][se] = v.w;
        }
        for (int i = t; i < HD * KC; i += 256) {
            const int kk = i & (KC - 1);
            const int h  = i >> 4;
            Wt[kk][h] = Wi[h * K1 + k0 + kk];
        }
        __syncthreads();
        gemm_chunk(acc, At, Wt, tr, tc);
    }
    #pragma unroll
    for (int i = 0; i < 4; ++i) {
        const long n = base + tr * 4 + i;
        if (n >= N_NODES) break;
        unsigned short* pp = Pb + n * HD + tc * 10;
        #pragma unroll
        for (int j = 0; j < 10; j += 2) {
            const float v0 = acc[i][j]     + bi[tc * 10 + j];
            const float v1 = acc[i][j + 1] + bi[tc * 10 + j + 1];
            *(ushort2*)(pp + j) = make_ushort2(f2b(v0), f2b(v1));
        }
    }
}

// ============================ H0 ===========================================
// Hb[e] = bf16(relu(Pb[src[e]] + Wi_e @ ea[e]))   — single K-chunk.
__global__ __launch_bounds__(256, 3)
void k_h0b_p(const float* __restrict__ ea, const int* __restrict__ src,
             const float* __restrict__ Wi, const unsigned short* __restrict__ Pb,
             unsigned short* __restrict__ Hb)
{
    __shared__ float At[KC][TE + 4];
    __shared__ float Wt[KC][WP];

    const int  t    = threadIdx.x;
    const long base = (long)blockIdx.x * TE;
    const int  se  = t >> 2;
    const int  skq = t & 3;
    const long ge  = base + se;
    const long gec = (ge < E_EDGES) ? ge : 0;
    const float* erow = ea + gec * BD;
    const int wk = t & 15, wh0 = t >> 4;
    const int tr = t >> 4, tc = t & 15;

    int es[4];
    #pragma unroll
    for (int i = 0; i < 4; ++i) {
        const long e = base + tr * 4 + i;
        es[i] = (e < E_EDGES) ? src[e] : 0;
    }

    #pragma unroll
    for (int j = 0; j < 4; ++j) {
        const int k = skq * 4 + j;
        At[k][se] = (k < BD) ? erow[k] : 0.f;
    }
    #pragma unroll
    for (int m = 0; m < 10; ++m)
        Wt[wk][wh0 + 16 * m] = (wk < BD) ? Wi[(wh0 + 16 * m) * K1 + HD + wk] : 0.f;

    ushort2 praw[4][5];
    #pragma unroll
    for (int i = 0; i < 4; ++i) {
        const unsigned short* prow = Pb + (long)es[i] * HD + tc * 10;
        #pragma unroll
        for (int q = 0; q < 5; ++q) praw[i][q] = *(const ushort2*)(prow + 2 * q);
    }

    __syncthreads();
    float acc[4][10];
    #pragma unroll
    for (int i = 0; i < 4; ++i)
        #pragma unroll
        for (int j = 0; j < 10; ++j) acc[i][j] = 0.f;
    gemm_chunk(acc, At, Wt, tr, tc);

    #pragma unroll
    for (int i = 0; i < 4; ++i) {
        const long e = base + tr * 4 + i;
        if (e >= E_EDGES) break;
        unsigned short* hp = Hb + e * HD + tc * 10;
        #pragma unroll
        for (int j = 0; j < 10; j += 2) {
            float v0 = acc[i][j]     + b2f(praw[i][j / 2].x);
            float v1 = acc[i][j + 1] + b2f(praw[i][j / 2].y);
            v0 = v0 > 0.f ? v0 : 0.f;
            v1 = v1 > 0.f ? v1 : 0.f;
            *(ushort2*)(hp + j) = make_ushort2(f2b(v0), f2b(v1));
        }
    }
}

// ============================ segment sum ==================================
// FINAL=0: write bf16 Sb. FINAL=1: write fp32 S with sum==0 -> x fallback.
template <int FINAL>
__global__ void k_segb(const unsigned short* __restrict__ Hb,
                       const int* __restrict__ ptr, const int* __restrict__ eid,
                       const float* __restrict__ x,
                       unsigned short* __restrict__ Sb, float* __restrict__ S)
{
    const int  lane = threadIdx.x & 63;
    const int  w    = threadIdx.x >> 6;
    const long n    = (long)blockIdx.x * 4 + w;
    if (n >= N_NODES) return;
    const int p0 = ptr[n], p1 = ptr[n + 1];
    float a0 = 0.f, a1 = 0.f, a2 = 0.f;
    for (int i = p0; i < p1; ++i) {
        const unsigned short* row = Hb + (long)eid[i] * HD;
        a0 += b2f(row[lane]);
        a1 += b2f(row[64 + lane]);
        if (lane < 32) a2 += b2f(row[128 + lane]);
    }
    const long sb = n * HD;
    if (FINAL) {
        float s = a0 + a1 + a2;
        #pragma unroll
        for (int off = 32; off > 0; off >>= 1) s += __shfl_xor(s, off, 64);
        if (s == 0.f) {
            S[sb + lane]      = x[sb + lane];
            S[sb + 64 + lane] = x[sb + 64 + lane];
            if (lane < 32) S[sb + 128 + lane] = x[sb + 128 + lane];
            return;
        }
        S[sb + lane]      = a0;
        S[sb + 64 + lane] = a1;
        if (lane < 32) S[sb + 128 + lane] = a2;
    } else {
        Sb[sb + lane]      = f2b(a0);
        Sb[sb + 64 + lane] = f2b(a1);
        if (lane < 32) Sb[sb + 128 + lane] = f2b(a2);
    }
}

// ============================ MFMA update, iter 1 ==========================
// Hb[e] = bf16(relu(Hb[e] + Wh @ (Sb[src[e]] - Hb[e^1]) + bh))
// (Hb still holds H0 = h0.)  8 waves x 16 edges; no barriers after staging.
__global__ __launch_bounds__(512, 6)
void k_updm1(const unsigned short* __restrict__ Sb,
             const int* __restrict__ src,
             const float* __restrict__ Wh, const float* __restrict__ bh,
             unsigned short* __restrict__ Hb)
{
    __shared__ unsigned short Whl[HD * WHP];   // 52480 B, [h][k] bf16

    const int t = threadIdx.x;
    for (int i = t * 4; i < HD * HD; i += 2048) {
        const int h = i / HD, k = i % HD;
        const float4 wv = *(const float4*)(Wh + h * HD + k);
        *(ushort4*)&Whl[h * WHP + k] =
            make_ushort4(f2b(wv.x), f2b(wv.y), f2b(wv.z), f2b(wv.w));
    }
    __syncthreads();

    const int  w    = t >> 6;
    const int  lane = t & 63;
    const int  cl   = lane & 15;     // A-row / B-col / C-col selector
    const int  kq   = lane >> 4;     // k-group 0..3
    const long base = (long)blockIdx.x * TM + w * 16;

    const long eA  = base + cl;
    const long eAs = (eA < E_EDGES) ? eA : 0;
    const int  sA  = src[eAs];
    const unsigned short* sbrow = Sb + (long)sA * HD + kq * 4;
    const unsigned short* rvrow = Hb + (eAs ^ 1) * HD + kq * 4;

    v4f acc[10];
    #pragma unroll
    for (int n = 0; n < 10; ++n) acc[n] = (v4f){0.f, 0.f, 0.f, 0.f};

    ushort4 ps = *(const ushort4*)(sbrow);
    ushort4 pr = *(const ushort4*)(rvrow);
    #pragma unroll
    for (int c = 0; c < 10; ++c) {
        const v4s a = mdiff(ps, pr);
        if (c < 9) {
            ps = *(const ushort4*)(sbrow + (c + 1) * KC);
            pr = *(const ushort4*)(rvrow + (c + 1) * KC);
        }
        #pragma unroll
        for (int n = 0; n < 10; ++n) {
            const v4s b = *(const v4s*)&Whl[(n * 16 + cl) * WHP + c * KC + kq * 4];
            acc[n] = __builtin_amdgcn_mfma_f32_16x16x16bf16_1k(a, b, acc[n], 0, 0, 0);
        }
    }

    #pragma unroll
    for (int n = 0; n < 10; ++n) {
        const int col = n * 16 + cl;
        const float bb = bh[col];
        #pragma unroll
        for (int rr = 0; rr < 4; ++rr) {
            const long e = base + kq * 4 + rr;
            if (e < E_EDGES) {
                unsigned short* hp = Hb + e * HD + col;
                float v = b2f(*hp) + acc[n][rr] + bb;
                v = v > 0.f ? v : 0.f;
                *hp = f2b(v);
            }
        }
    }
}

// ============================ MFMA update, iter 2 ==========================
// h0 = relu(Pb[src] + ea @ Wi_e^T)  (Q via one MFMA step vs Wie LDS tile)
// Hb[e] = bf16(relu(h0 + Wh @ (Sb[src[e]] - Hb[e^1]) + bh))
__global__ __launch_bounds__(512, 4)
void k_updm2(const unsigned short* __restrict__ Sb,
             const float* __restrict__ ea, const int* __restrict__ src,
             const float* __restrict__ Wi, const float* __restrict__ Wh,
             const float* __restrict__ bh,
             const unsigned short* __restrict__ Pb,
             unsigned short* __restrict__ Hb)
{
    __shared__ unsigned short Whl[HD * WHP];    // 52480 B
    __shared__ unsigned short Wie[HD * WIEP];   // 6400 B, [col][k'] bf16

    const int t = threadIdx.x;
    for (int i = t * 4; i < HD * HD; i += 2048) {
        const int h = i / HD, k = i % HD;
        const float4 wv = *(const float4*)(Wh + h * HD + k);
        *(ushort4*)&Whl[h * WHP + k] =
            make_ushort4(f2b(wv.x), f2b(wv.y), f2b(wv.z), f2b(wv.w));
    }
    if (t < HD) {
        const float* wr = Wi + (long)t * K1 + HD;
        #pragma unroll
        for (int k = 0; k < BD; ++k) Wie[t * WIEP + k] = f2b(wr[k]);
        Wie[t * WIEP + 14] = 0;
        Wie[t * WIEP + 15] = 0;
    }
    __syncthreads();

    const int  w    = t >> 6;
    const int  lane = t & 63;
    const int  cl   = lane & 15;
    const int  kq   = lane >> 4;
    const long base = (long)blockIdx.x * TM + w * 16;

    const long eA  = base + cl;
    const long eAs = (eA < E_EDGES) ? eA : 0;
    const int  sA  = src[eAs];
    const unsigned short* sbrow = Sb + (long)sA * HD + kq * 4;
    const unsigned short* rvrow = Hb + (eAs ^ 1) * HD + kq * 4;

    // ---- Q: A-frag from ea row (k' = kq*4+j, mask >= BD) ----
    v4s aq;
    {
        const float* earow = ea + eAs * BD;
        #pragma unroll
        for (int j = 0; j < 4; ++j) {
            const int k = kq * 4 + j;
            aq[j] = (short)((k < BD) ? f2b(earow[k]) : 0);
        }
    }
    int srcC[4];
    #pragma unroll
    for (int rr = 0; rr < 4; ++rr) {
        const long e = base + kq * 4 + rr;
        srcC[rr] = src[(e < E_EDGES) ? e : 0];
    }

    // h0 = relu(Pb gather + Q)
    float h0[10][4];
    #pragma unroll
    for (int n = 0; n < 10; ++n) {
        const v4s bq = *(const v4s*)&Wie[(n * 16 + cl) * WIEP + kq * 4];
        v4f q = __builtin_amdgcn_mfma_f32_16x16x16bf16_1k(
                    aq, bq, (v4f){0.f, 0.f, 0.f, 0.f}, 0, 0, 0);
        const int col = n * 16 + cl;
        #pragma unroll
        for (int rr = 0; rr < 4; ++rr) {
            const float pv = b2f(Pb[(long)srcC[rr] * HD + col]);
            const float v  = pv + q[rr];
            h0[n][rr] = v > 0.f ? v : 0.f;
        }
    }

    // ---- Wh @ (Sb - Hbrev) ----
    v4f acc[10];
    #pragma unroll
    for (int n = 0; n < 10; ++n) acc[n] = (v4f){0.f, 0.f, 0.f, 0.f};

    ushort4 ps = *(const ushort4*)(sbrow);
    ushort4 pr = *(const ushort4*)(rvrow);
    #pragma unroll
    for (int c = 0; c < 10; ++c) {
        const v4s a = mdiff(ps, pr);
        if (c < 9) {
            ps = *(const ushort4*)(sbrow + (c + 1) * KC);
            pr = *(const ushort4*)(rvrow + (c + 1) * KC);
        }
        #pragma unroll
        for (int n = 0; n < 10; ++n) {
            const v4s b = *(const v4s*)&Whl[(n * 16 + cl) * WHP + c * KC + kq * 4];
            acc[n] = __builtin_amdgcn_mfma_f32_16x16x16bf16_1k(a, b, acc[n], 0, 0, 0);
        }
    }

    #pragma unroll
    for (int n = 0; n < 10; ++n) {
        const int col = n * 16 + cl;
        const float bb = bh[col];
        #pragma unroll
        for (int rr = 0; rr < 4; ++rr) {
            const long e = base + kq * 4 + rr;
            if (e < E_EDGES) {
                float v = h0[n][rr] + acc[n][rr] + bb;
                v = v > 0.f ? v : 0.f;
                Hb[e * HD + col] = f2b(v);
            }
        }
    }
}

// ============================ output =======================================
__global__ __launch_bounds__(256, 2)
void k_out(const float* __restrict__ x, const float* __restrict__ Mg,
           const float* __restrict__ Wo, const float* __restrict__ bo,
           float* __restrict__ out)
{
    __shared__ float At[KC][TE + 4];
    __shared__ float Wt[KC][WP];

    const int  t    = threadIdx.x;
    const long base = (long)blockIdx.x * TE;
    const int  se  = t >> 2;
    const int  skq = t & 3;
    const long gn  = base + se;
    const bool ev  = gn < N_NODES;
    const long gnc = ev ? gn : 0;
    const float* xrow = x  + gnc * HD;
    const float* mrow = Mg + gnc * HD;
    const int tr = t >> 4, tc = t & 15;

    float acc[4][10];
    #pragma unroll
    for (int i = 0; i < 4; ++i)
        #pragma unroll
        for (int j = 0; j < 10; ++j) acc[i][j] = 0.f;

    for (int c = 0; c < KO / KC; ++c) {
        const int k0 = c * KC;
        __syncthreads();
        {
            const int kb = k0 + skq * 4;
            const float4 v = (kb < HD) ? *(const float4*)(xrow + kb)
                                       : *(const float4*)(mrow + (kb - HD));
            At[skq * 4 + 0][se] = v.x;
            At[skq * 4 + 1][se] = v.y;
            At[skq * 4 + 2][se] = v.z;
            At[skq * 4 + 3][se] = v.w;
        }
        for (int i = t; i < HD * KC; i += 256) {
            const int kk = i & (KC - 1);
            const int h  = i >> 4;
            Wt[kk][h] = Wo[h * KO + k0 + kk];
        }
        __syncthreads();
        gemm_chunk(acc, At, Wt, tr, tc);
    }
    #pragma unroll
    for (int i = 0; i < 4; ++i) {
        const long n = base + tr * 4 + i;
        if (n >= N_NODES) break;
        float* op = out + n * HD + tc * 10;
        #pragma unroll
        for (int j = 0; j < 10; j += 2) {
            float v0 = acc[i][j]     + bo[tc * 10 + j];
            float v1 = acc[i][j + 1] + bo[tc * 10 + j + 1];
            v0 = v0 > 0.f ? v0 : 0.f;
            v1 = v1 > 0.f ? v1 : 0.f;
            *(float2*)(op + j) = make_float2(v0, v1);
        }
    }
}

// ---------------------------------------------------------------------------
extern "C" void kernel_launch(void* const* d_in, const int* in_sizes, int n_in,
                              void* d_out, int out_size, void* d_ws, size_t ws_size,
                              hipStream_t stream)
{
    const float* x  = (const float*)d_in[0];
    const float* ea = (const float*)d_in[1];
    const int*   ei = (const int*)d_in[2];
    const float* Wi = (const float*)d_in[4];
    const float* bi = (const float*)d_in[5];
    const float* Wh = (const float*)d_in[6];
    const float* bh = (const float*)d_in[7];
    const float* Wo = (const float*)d_in[8];
    const float* bo = (const float*)d_in[9];
    float* out = (float*)d_out;

    const int* src = ei;
    const int* dst = ei + E_EDGES;

    const int gE  = (E_EDGES + TE - 1) / TE;      // 7813
    const int gM  = (E_EDGES + TM - 1) / TM;      // 3907
    const int gN  = (N_NODES + TE - 1) / TE;      // 782
    const int gF  = (N_NODES + 3) / 4;            // 12500
    const int gEe = (E_EDGES + 255) / 256;        // 1954

    // ws: Hb bf16 (160e6) | Mf fp32 (32e6) | CSR (~2.6e6)  -> 194.6e6 proven
    char* w = (char*)d_ws;
    unsigned short* Hb = (unsigned short*)(w);
    float* Mf  = (float*)(w + 160000000);
    int*   ptr = (int*)  (w + 192000000);
    int*   cnt = (int*)  (w + 192200016);
    int*   cur = (int*)  (w + 192400016);
    int*   eid = (int*)  (w + 192600016);
    // d_out hosts Pb (16e6) + Sb (16e6) until k_out.
    unsigned short* Pb = (unsigned short*)d_out;
    unsigned short* Sb = (unsigned short*)((char*)d_out + 16000000);

    k_zero<<<(100000 + 1023) / 1024, 256, 0, stream>>>((float*)cnt, 100000);
    k_csr_count<<<gEe, 256, 0, stream>>>(dst, cnt);
    k_csr_scan<<<1, 1024, 0, stream>>>(cnt, ptr);
    k_csr_fill<<<gEe, 256, 0, stream>>>(dst, ptr, cur, eid);

    k_nodeproj<<<gN, 256, 0, stream>>>(x, Wi, bi, Pb);
    k_h0b_p<<<gE, 256, 0, stream>>>(ea, src, Wi, Pb, Hb);                 // H0
    k_segb<0><<<gF, 256, 0, stream>>>(Hb, ptr, eid, x, Sb, nullptr);      // S0
    k_updm1<<<gM, 512, 0, stream>>>(Sb, src, Wh, bh, Hb);                 // H1
    k_segb<0><<<gF, 256, 0, stream>>>(Hb, ptr, eid, x, Sb, nullptr);      // S1
    k_updm2<<<gM, 512, 0, stream>>>(Sb, ea, src, Wi, Wh, bh, Pb, Hb);     // H2
    k_segb<1><<<gF, 256, 0, stream>>>(Hb, ptr, eid, x, nullptr, Mf);      // M
    k_out<<<gN, 256, 0, stream>>>(x, Mf, Wo, bo, out);
}